// Round 13
// baseline (389.752 us; speedup 1.0000x reference)
//
#include <hip/hip_runtime.h>
#include <hip/hip_bf16.h>

// B=32, C=3, H=W=128, D=512, K=512, S=4, NPOS=32768
#define NPOS 32768
#define EPS_GAP 4e-3f
#define MAXSUS 4096

typedef __attribute__((ext_vector_type(8))) short short8;
typedef __attribute__((ext_vector_type(4))) float floatx4;

static __device__ __forceinline__ float bfu(unsigned short h) {
    return __uint_as_float(((unsigned int)h) << 16);
}
static __device__ __forceinline__ unsigned short f2bf(float f) {
    unsigned int u = __float_as_uint(f);
    u = (u + 0x7fffu + ((u >> 16) & 1u)) >> 16;   // RNE
    return (unsigned short)u;
}
static __device__ __forceinline__ float ldin(const void* p, size_t i, int flag) {
    return flag ? bfu(((const unsigned short*)p)[i]) : ((const float*)p)[i];
}

// LDS-only barrier: drains ds ops (lgkmcnt) but leaves global loads/stores
// in flight across the barrier (no vmcnt(0) drain) — this is what lets the
// B-fragment prefetch survive the phase boundary.
static __device__ __forceinline__ void ldsbar() {
    asm volatile("s_waitcnt lgkmcnt(0)" ::: "memory");
    __builtin_amdgcn_s_barrier();
    asm volatile("" ::: "memory");
}

// Swizzled B-fragment offset for the CODEBOOK (units: shorts).
static __device__ __forceinline__ size_t swzoff(int k, int d) {
    return (size_t)(d >> 5) * 16384 + (size_t)(k >> 4) * 512
         + (size_t)((((d >> 3) & 3) * 16 + (k & 15)) * 8) + (d & 7);
}

// ---------------------------------------------------------------------------
// Sniff: decide bf16 vs fp32 input encoding from codebook column norms.
// ---------------------------------------------------------------------------
__global__ __launch_bounds__(1024) void k_sniff(const void* __restrict__ cb,
                                                int* __restrict__ flag,
                                                int* __restrict__ scnt) {
    __shared__ float s[1024];
    const int t = threadIdx.x;
    const int k = t & 63, g = t >> 6;          // 16 groups x 32 d
    const unsigned short* u = (const unsigned short*)cb;
    float acc = 0.f;
    for (int d = g * 32; d < g * 32 + 32; ++d) {
        float v = bfu(u[(size_t)d * 512 + k]);
        acc = fmaf(v, v, acc);
    }
    s[t] = acc;
    __syncthreads();
    if (t < 64) {
        float a = 0.f;
        #pragma unroll
        for (int g2 = 0; g2 < 16; ++g2) a += s[g2 * 64 + k];
        int ok = (a >= 100.f && a <= 2000.f) ? 1 : 0;
        unsigned long long m = __ballot(ok);
        if (k == 0) {
            *flag = (m == ~0ull) ? 1 : 0;
            *scnt = 0;
        }
    }
}

// ---------------------------------------------------------------------------
// FUSED prep: one launch, role-split by blockIdx. NO cross-role dependencies.
//   bid   0..194 : canonW   (We/be/Wd/bd -> canonical fp32)       [reads raw]
//   bid 195..258 : prepcb   (cb -> cbT; cbHS/cbLS swizzled bf16)  [reads raw cb]
//   bid 259..266 : w2       (column norms)                        [reads raw cb]
//   bid 267..394 : udec     (decoder LUT U[k][48])                [reads raw]
//   bid 395..402 : weswz    (We -> H/L bf16 B-fragment tables, K-padded to 64)
// ---------------------------------------------------------------------------
__global__ __launch_bounds__(256) void k_prepAll(
        const void* __restrict__ We, const void* __restrict__ be,
        const void* __restrict__ Wd, const void* __restrict__ bd,
        const void* __restrict__ cb, const int* __restrict__ flagp,
        float* __restrict__ cWe, float* __restrict__ cbe,
        float* __restrict__ cWd, float* __restrict__ cbd,
        float* __restrict__ cbT, unsigned short* __restrict__ cbHS,
        unsigned short* __restrict__ cbLS,
        unsigned short* __restrict__ WeswzH, unsigned short* __restrict__ WeswzL,
        float* __restrict__ w2, double* __restrict__ w2d,
        float* __restrict__ U) {
    __shared__ float tile[64][65];
    __shared__ double sd[256];
    const int bid = blockIdx.x;
    const int t = threadIdx.x;
    const int flag = *flagp;

    if (bid < 195) {
        // ---- canonW ----
        int e = bid * 256 + t;
        if (e < 24576)       cWe[e]         = ldin(We, e, flag);
        else if (e < 25088)  cbe[e - 24576] = ldin(be, e - 24576, flag);
        else if (e < 49664)  cWd[e - 25088] = ldin(Wd, e - 25088, flag);
        else if (e < 49667)  cbd[e - 49664] = ldin(bd, e - 49664, flag);
    } else if (bid < 259) {
        // ---- prepcb ----
        const int bb = bid - 195;
        const int D0 = (bb >> 3) * 64, K0 = (bb & 7) * 64;
        for (int it = 0; it < 16; ++it) {
            int r = (t >> 6) + 4 * it, c = t & 63;
            tile[r][c] = ldin(cb, (size_t)(D0 + r) * 512 + K0 + c, flag);
        }
        __syncthreads();
        for (int it = 0; it < 16; ++it) {
            int r = (t >> 6) + 4 * it, c = t & 63;
            float v = tile[c][r];
            int k = K0 + r, d = D0 + c;
            cbT[(size_t)k * 512 + d] = v;
            size_t o2 = swzoff(k, d);
            unsigned short h = f2bf(v);
            cbHS[o2] = h;
            cbLS[o2] = f2bf(v - bfu(h));
        }
    } else if (bid < 267) {
        // ---- w2 ----
        const int k = (bid - 259) * 64 + (t & 63);
        const int g = t >> 6;                  // 4 groups x 128 d
        double acc = 0.0;
        for (int d = g * 128; d < g * 128 + 128; ++d) {
            double v = (double)ldin(cb, (size_t)d * 512 + k, flag);
            acc += v * v;
        }
        sd[t] = acc;
        __syncthreads();
        if (t < 64) {
            double a = sd[t] + sd[t + 64] + sd[t + 128] + sd[t + 192];
            w2[k] = (float)a;
            w2d[k] = a;
        }
    } else if (bid < 395) {
        // ---- udec: U[k][c*16+u*4+v] = sum_d cb[d][k]*Wd[c][d][3-u][3-v]+bd[c]
        const int kk = (bid - 267) * 4 + (t >> 6);
        const int lane = t & 63;
        const int j = lane >> 2, dpart = lane & 3;
        const int u = (j >> 2) & 3, v = j & 3;
        int woff[3];
        #pragma unroll
        for (int m = 0; m < 3; ++m) woff[m] = m * 8192 + (3 - u) * 4 + (3 - v);
        float a0 = 0.f, a1 = 0.f, a2 = 0.f;
        for (int i = 0; i < 128; ++i) {
            int d = dpart * 128 + i;
            float cw = ldin(cb, (size_t)d * 512 + kk, flag);
            a0 = fmaf(cw, ldin(Wd, (size_t)(woff[0] + d * 16), flag), a0);
            a1 = fmaf(cw, ldin(Wd, (size_t)(woff[1] + d * 16), flag), a1);
            a2 = fmaf(cw, ldin(Wd, (size_t)(woff[2] + d * 16), flag), a2);
        }
        a0 += __shfl_xor(a0, 1); a0 += __shfl_xor(a0, 2);
        a1 += __shfl_xor(a1, 1); a1 += __shfl_xor(a1, 2);
        a2 += __shfl_xor(a2, 1); a2 += __shfl_xor(a2, 2);
        if (dpart == 0) {
            U[kk * 48 +  0 + j] = a0 + ldin(bd, 0, flag);
            U[kk * 48 + 16 + j] = a1 + ldin(bd, 1, flag);
            U[kk * 48 + 32 + j] = a2 + ldin(bd, 2, flag);
        }
    } else {
        // ---- weswz: We[d][q<48] (q 48..63 zero) -> H/L B-fragment tables.
        const int bid2 = bid - 395;            // 0..7
        for (int it = 0; it < 16; ++it) {
            int e = bid2 * 4096 + it * 256 + t;    // over 512*64
            int d = e >> 6, q = e & 63;
            float w = (q < 48) ? ldin(We, (size_t)d * 48 + q, flag) : 0.f;
            unsigned short h = f2bf(w);
            unsigned short l = f2bf(w - bfu(h));
            size_t off = (size_t)((d >> 5) * 2 + ((d >> 4) & 1)) * 1024
                       + (size_t)(q >> 5) * 512
                       + (size_t)((((q >> 3) & 3) * 16 + (d & 15)) * 8) + (q & 7);
            WeswzH[off] = h;
            WeswzL[off] = l;
        }
    }
}

// ---------------------------------------------------------------------------
// conv via MFMA (r12-verified): Z[64 pos][32 d] = patch x We, split-precision.
// ---------------------------------------------------------------------------
static __device__ __forceinline__ void conv_mfma(
        const unsigned short* __restrict__ patchH, const unsigned short* __restrict__ patchL,
        const unsigned short* __restrict__ WeH, const unsigned short* __restrict__ WeL,
        const float* __restrict__ cbe, int dc, int wave, int lane, int flag,
        unsigned short* __restrict__ zq, float* __restrict__ out_z, int b, int SP0) {
    const int mt = wave >> 1, nt = wave & 1;
    const int quad = lane >> 4, lcol = lane & 15;
    const int row = mt * 16 + lcol;
    short8 aH0 = *(const short8*)(patchH + row * 72 + quad * 8);
    short8 aH1 = *(const short8*)(patchH + row * 72 + 32 + quad * 8);
    const unsigned short* wb = WeH + (size_t)((dc >> 5) * 2 + nt) * 1024 + lane * 8;
    short8 bH0 = *(const short8*)(wb);
    short8 bH1 = *(const short8*)(wb + 512);
    floatx4 c = (floatx4){0.f, 0.f, 0.f, 0.f};
    c = __builtin_amdgcn_mfma_f32_16x16x32_bf16(aH0, bH0, c, 0, 0, 0);
    c = __builtin_amdgcn_mfma_f32_16x16x32_bf16(aH1, bH1, c, 0, 0, 0);
    if (!flag) {   // fp32 inputs: add L*H and H*L terms
        short8 aL0 = *(const short8*)(patchL + row * 72 + quad * 8);
        short8 aL1 = *(const short8*)(patchL + row * 72 + 32 + quad * 8);
        const unsigned short* wl = WeL + (size_t)((dc >> 5) * 2 + nt) * 1024 + lane * 8;
        short8 bL0 = *(const short8*)(wl);
        short8 bL1 = *(const short8*)(wl + 512);
        c = __builtin_amdgcn_mfma_f32_16x16x32_bf16(aL0, bH0, c, 0, 0, 0);
        c = __builtin_amdgcn_mfma_f32_16x16x32_bf16(aL1, bH1, c, 0, 0, 0);
        c = __builtin_amdgcn_mfma_f32_16x16x32_bf16(aH0, bL0, c, 0, 0, 0);
        c = __builtin_amdgcn_mfma_f32_16x16x32_bf16(aH1, bL1, c, 0, 0, 0);
    }
    const int d = nt * 16 + lcol;
    const float bias = cbe[dc + d];
    const int p0 = mt * 16 + quad * 4;        // 4 consecutive positions
    float zf[4];
    #pragma unroll
    for (int r = 0; r < 4; ++r) {
        float z = fmaxf(c[r] + bias, 0.f);
        unsigned short h = f2bf(z);
        unsigned short l = f2bf(z - bfu(h));
        zq[(p0 + r) * 40 + d] = h;
        zq[2560 + (p0 + r) * 40 + d] = l;
        zf[r] = bfu(h) + bfu(l);
    }
    *(float4*)(out_z + (size_t)(b * 512 + dc + d) * 1024 + SP0 + p0) =
        (float4){zf[0], zf[1], zf[2], zf[3]};
}

// ---------------------------------------------------------------------------
// Distance mfma_step: B-H fragments arrive PRE-LOADED in registers (prefetched
// one phase ahead); the !flag bL path loads inline (fp32 mode only).
// MFMA order identical to r12 -> bit-identical acc.
// ---------------------------------------------------------------------------
static __device__ __forceinline__ void mfma_step(
        const unsigned short* __restrict__ zq,
        short8 b0, short8 b1, short8 b2, short8 b3,
        const unsigned short* __restrict__ cbLS,
        int dcPrev, int wave, int quad, int lcol, int flag, floatx4 (&acc)[4][4]) {
    const int lane = quad * 16 + lcol;
    short8 aH[4], aL[4];
    #pragma unroll
    for (int mt = 0; mt < 4; ++mt) {
        aH[mt] = *(const short8*)(zq + (mt * 16 + lcol) * 40 + quad * 8);
        aL[mt] = *(const short8*)(zq + 2560 + (mt * 16 + lcol) * 40 + quad * 8);
    }
    #pragma unroll
    for (int j = 0; j < 4; ++j) {
        short8 bH = (j == 0) ? b0 : (j == 1) ? b1 : (j == 2) ? b2 : b3;
        #pragma unroll
        for (int mt = 0; mt < 4; ++mt) {
            acc[mt][j] = __builtin_amdgcn_mfma_f32_16x16x32_bf16(aH[mt], bH, acc[mt][j], 0, 0, 0);
            acc[mt][j] = __builtin_amdgcn_mfma_f32_16x16x32_bf16(aL[mt], bH, acc[mt][j], 0, 0, 0);
        }
    }
    if (!flag) {   // fp32 inputs: third term zh*cbL (inline loads)
        const unsigned short* fbL = cbLS + (size_t)dcPrev * 512 + (size_t)(wave * 4) * 512 + lane * 8;
        #pragma unroll
        for (int j = 0; j < 4; ++j) {
            short8 bL = *(const short8*)(fbL + j * 512);
            #pragma unroll
            for (int mt = 0; mt < 4; ++mt)
                acc[mt][j] = __builtin_amdgcn_mfma_f32_16x16x32_bf16(aH[mt], bL, acc[mt][j], 0, 0, 0);
        }
    }
}

// best/second combine: (a1,ak,a2) <- merge (o1,ok,o2). Order-independent
// tournament (ties -> gap 0), so reshaping the reduction tree is safe.
static __device__ __forceinline__ void bmerge(float& a1, int& ak, float& a2,
                                              float o1, int ok, float o2) {
    if (o1 < a1)      { a2 = fminf(a1, o2); a1 = o1; ak = ok; }
    else if (o1 > a1) { a2 = fminf(a2, o1); }
    else              { a2 = a1; if (ok < ak) ak = ok; }
}

// ---------------------------------------------------------------------------
// k_main v15 = v14 + one-phase-ahead register prefetch of the 4 distance-B
// fragments (coalesced cbHS loads issued during phase dc, consumed in phase
// dc+32; they stay in flight across ldsbar since it never drains vmcnt).
// LDS: patchH 9216 | patchL 9216 | zb 2 pairs x 10240 = 38912B.
// ---------------------------------------------------------------------------
__global__ __launch_bounds__(512, 4) void k_main(
        const void* __restrict__ x, const unsigned short* __restrict__ WeswzH,
        const unsigned short* __restrict__ WeswzL,
        const float* __restrict__ cbe, const int* __restrict__ flagp,
        const unsigned short* __restrict__ cbHS, const unsigned short* __restrict__ cbLS,
        const float* __restrict__ cbT, const float* __restrict__ w2,
        float* __restrict__ out_z, float* __restrict__ out_e,
        int* __restrict__ idx, int* __restrict__ scnt, int* __restrict__ spos,
        int skipTail) {
    __shared__ __align__(16) char smc[38912];
    unsigned short* patchH = (unsigned short*)smc;            // [64][72]
    unsigned short* patchL = (unsigned short*)(smc + 9216);   // [64][72]
    unsigned short* zb = (unsigned short*)(smc + 18432);      // 2 pairs x 5120 shorts

    const int t = threadIdx.x;
    const int bid = blockIdx.x;
    const int q = ((bid & 7) << 6) | (bid >> 3);   // XCD co-location swizzle
    const int P0 = q * 64;
    const int b = P0 >> 10, SP0 = P0 & 1023;
    const int flag = *flagp;
    const int wave = t >> 6, lane = t & 63;
    const int quad = lane >> 4, lcol = lane & 15;

    // stage x patches once as bf16 H/L, K-padded with zeros (q 48..63)
    for (int e = t; e < 4096; e += 512) {
        int pid = e >> 6, qq = e & 63;
        float xv = 0.f;
        if (qq < 48) {
            int c = qq >> 4, r = (qq >> 2) & 3, s = qq & 3;
            int pos = P0 + pid;
            int bb = pos >> 10, sp = pos & 1023, i = sp >> 5, j = sp & 31;
            xv = ldin(x, ((bb * 3 + c) * 128 + (i * 4 + r)) * 128 + (j * 4 + s), flag);
        }
        unsigned short h = f2bf(xv);
        patchH[pid * 72 + qq] = h;
        patchL[pid * 72 + qq] = f2bf(xv - bfu(h));
    }

    floatx4 acc[4][4];
    #pragma unroll
    for (int mt = 0; mt < 4; ++mt)
        #pragma unroll
        for (int j = 0; j < 4; ++j) acc[mt][j] = (floatx4){0.f, 0.f, 0.f, 0.f};

    // B-fragment prefetch registers (chunk whose distance-MFMA runs NEXT phase)
    short8 bp0, bp1, bp2, bp3;
    {
        const unsigned short* f = cbHS + (size_t)(wave * 4) * 512 + lane * 8;
        bp0 = *(const short8*)(f);
        bp1 = *(const short8*)(f + 512);
        bp2 = *(const short8*)(f + 1024);
        bp3 = *(const short8*)(f + 1536);
    }

    ldsbar();
    conv_mfma(patchH, patchL, WeswzH, WeswzL, cbe, 0, wave, lane, flag,
              zb, out_z, b, SP0);                             // chunk 0 -> pair 0
    for (int dc = 32; dc < 512; dc += 32) {
        ldsbar();
        const int p = (dc >> 5) & 1;
        conv_mfma(patchH, patchL, WeswzH, WeswzL, cbe, dc, wave, lane, flag,
                  zb + p * 5120, out_z, b, SP0);
        // consume prev-phase prefetch; issue next prefetch
        short8 c0 = bp0, c1 = bp1, c2 = bp2, c3 = bp3;
        {
            const unsigned short* f = cbHS + (size_t)dc * 512 + (size_t)(wave * 4) * 512 + lane * 8;
            bp0 = *(const short8*)(f);
            bp1 = *(const short8*)(f + 512);
            bp2 = *(const short8*)(f + 1024);
            bp3 = *(const short8*)(f + 1536);
        }
        mfma_step(zb + (p ^ 1) * 5120, c0, c1, c2, c3, cbLS, dc - 32,
                  wave, quad, lcol, flag, acc);
    }
    ldsbar();
    mfma_step(zb + 5120, bp0, bp1, bp2, bp3, cbLS, 480, wave, quad, lcol, flag, acc);

    // ---- epilogue: per-lane best/second over its 4 codes, then shuffle ----
    float s1[4][4], s2[4][4]; int k1[4][4];
    #pragma unroll
    for (int mt = 0; mt < 4; ++mt)
        #pragma unroll
        for (int r = 0; r < 4; ++r) { s1[mt][r] = 1e30f; s2[mt][r] = 1e30f; k1[mt][r] = 511; }
    #pragma unroll
    for (int j = 0; j < 4; ++j) {
        int code = (wave * 4 + j) * 16 + lcol;
        float wk = w2[code];
        #pragma unroll
        for (int mt = 0; mt < 4; ++mt)
            #pragma unroll
            for (int r = 0; r < 4; ++r) {
                float s = wk - 2.f * acc[mt][j][r];
                bmerge(s1[mt][r], k1[mt][r], s2[mt][r], s, code, 1e30f);
            }
    }
    // overlay reduction arrays on patchH region (patch dead after last conv+bar)
    float* sS1 = (float*)smc;             // [64 pos][8 wave]
    int*   sK1 = (int*)(smc + 2048);
    float* sS2 = (float*)(smc + 4096);
    int*   ii  = (int*)(smc + 6144);      // [64]
    #pragma unroll
    for (int mt = 0; mt < 4; ++mt)
        #pragma unroll
        for (int r = 0; r < 4; ++r) {
            float a1 = s1[mt][r], a2 = s2[mt][r]; int ak = k1[mt][r];
            #pragma unroll
            for (int m = 1; m < 16; m <<= 1) {
                float o1 = __shfl_xor(a1, m);
                float o2 = __shfl_xor(a2, m);
                int   ok = __shfl_xor(ak, m);
                bmerge(a1, ak, a2, o1, ok, o2);
            }
            if (lcol == 0) {
                int pos = mt * 16 + quad * 4 + r;
                sS1[pos * 8 + wave] = a1;
                sK1[pos * 8 + wave] = ak;
                sS2[pos * 8 + wave] = a2;
            }
        }
    __syncthreads();
    if (t < 64) {
        float a1 = sS1[t * 8]; int ak = sK1[t * 8]; float a2 = sS2[t * 8];
        #pragma unroll
        for (int w = 1; w < 8; ++w)
            bmerge(a1, ak, a2, sS1[t * 8 + w], sK1[t * 8 + w], sS2[t * 8 + w]);
        ak &= 511;
        ii[t] = ak;
        unsigned int flagged = 0u;
        if (a2 - a1 < EPS_GAP) {
            int slot = atomicAdd(scnt, 1);
            if (slot < MAXSUS) { spos[slot] = P0 + t; flagged = 1u; }
        }
        idx[P0 + t] = (int)((unsigned)ak | (flagged << 31));
    }
    __syncthreads();

    // ---- fused emb: out_e[b][d][SP0+sp] = cbT[ii[sp]][d] ----
    const int sp = t & 63, dq = t >> 6;   // 8 groups x 64 d
    const float* row = cbT + (size_t)ii[sp] * 512;
    const size_t obase = ((size_t)b * 512) * 1024 + SP0 + sp;
    for (int d0 = dq * 64; d0 < dq * 64 + 64; d0 += 4) {
        if (skipTail && b == 31 && d0 >= 448) break;
        float4 v = *(const float4*)(row + d0);
        out_e[obase + (size_t)(d0    ) * 1024] = v.x;
        out_e[obase + (size_t)(d0 + 1) * 1024] = v.y;
        out_e[obase + (size_t)(d0 + 2) * 1024] = v.z;
        out_e[obase + (size_t)(d0 + 3) * 1024] = v.w;
    }
}

// ---------------------------------------------------------------------------
// FUSED post: recon (bid 0..127) ∥ rescore (bid 128..383) in one launch.
// ---------------------------------------------------------------------------
__global__ __launch_bounds__(256) void k_post(
        const float* __restrict__ out_z, const void* __restrict__ cb,
        const double* __restrict__ w2d, int* __restrict__ idx,
        const int* __restrict__ scnt, const int* __restrict__ spos,
        const float* __restrict__ U, const int* __restrict__ flagp,
        float* __restrict__ out_e, float* __restrict__ out_r, int skipTail) {
    __shared__ float zsh[512];
    __shared__ float rs[256];
    __shared__ int rk[256];
    __shared__ int bc[2];
    const int bid = blockIdx.x;
    const int t = threadIdx.x;

    if (bid < 128) {
        // ---- recon role ----
        const int pos = bid * 256 + t;
        const int v0 = idx[pos];
        if (v0 >= 0) {
            const int id = v0 & 511;
            const int b = pos >> 10, sp = pos & 1023, i = sp >> 5, j = sp & 31;
            const float* u = &U[(size_t)id * 48];
            #pragma unroll
            for (int c = 0; c < 3; ++c)
                #pragma unroll
                for (int uu = 0; uu < 4; ++uu) {
                    float4 q = *(const float4*)(&u[c * 16 + uu * 4]);
                    float4 o;
                    o.x = 1.f / (1.f + __expf(-q.x));
                    o.y = 1.f / (1.f + __expf(-q.y));
                    o.z = 1.f / (1.f + __expf(-q.z));
                    o.w = 1.f / (1.f + __expf(-q.w));
                    *(float4*)(&out_r[((size_t)((b * 3 + c) * 128) + (i * 4 + uu)) * 128 + j * 4]) = o;
                }
        }
        return;
    }

    // ---- rescore role (256 blocks) ----
    const int flag = *flagp;
    int n = *scnt; if (n > MAXSUS) n = MAXSUS;
    for (int s = bid - 128; s < n; s += 256) {
        int p = spos[s] & 32767;
        int b = p >> 10, sp = p & 1023;
        __syncthreads();
        zsh[t]       = out_z[(size_t)(b * 512 + t) * 1024 + sp];
        zsh[t + 256] = out_z[(size_t)(b * 512 + t + 256) * 1024 + sp];
        __syncthreads();
        float bs = 1e30f; int bk = 511;
        for (int cc = 0; cc < 2; ++cc) {
            int k = t + cc * 256;
            double a = 0.0;
            for (int d = 0; d < 512; ++d)
                a = fma((double)zsh[d], (double)ldin(cb, (size_t)d * 512 + k, flag), a);
            float sc = (float)(w2d[k] - 2.0 * a);
            if (sc < bs || (sc == bs && k < bk)) { bs = sc; bk = k; }
        }
        rs[t] = bs; rk[t] = bk;
        __syncthreads();
        for (int str = 128; str > 0; str >>= 1) {
            if (t < str) {
                float so = rs[t + str]; int ko = rk[t + str];
                if (so < rs[t] || (so == rs[t] && ko < rk[t])) { rs[t] = so; rk[t] = ko; }
            }
            __syncthreads();
        }
        if (t == 0) {
            int kstar = rk[0] & 511;
            int old = idx[p] & 511;
            bc[0] = kstar; bc[1] = (kstar != old);
            idx[p] = kstar;                       // clears suspect flag too
        }
        __syncthreads();
        const int kk = bc[0];
        if (bc[1]) {
            for (int d = t; d < 512; d += 256) {
                if (skipTail && b == 31 && d >= 448) continue;
                out_e[(size_t)(b * 512 + d) * 1024 + sp] = ldin(cb, (size_t)d * 512 + kk, flag);
            }
        }
        // recon for this suspect (recon role skipped it) — always write
        if (t < 48) {
            float q = U[(size_t)kk * 48 + t];
            float o = 1.f / (1.f + __expf(-q));
            int c = t >> 4, uu = (t >> 2) & 3, vv = t & 3;
            int i = sp >> 5, j = sp & 31;
            out_r[((size_t)((b * 3 + c) * 128) + (i * 4 + uu)) * 128 + j * 4 + vv] = o;
        }
    }
}

// ---------------------------------------------------------------------------
// Widened fixup: 64 blocks, one d-row each. Coalesced idx read + row write.
// ---------------------------------------------------------------------------
__global__ __launch_bounds__(1024) void k_fixup(
        const void* __restrict__ cb, const int* __restrict__ flagp,
        const int* __restrict__ idx, float* __restrict__ out_e) {
    const int t = threadIdx.x;
    const int d = 448 + blockIdx.x;
    const int flag = *flagp;
    const int id = idx[31744 + t] & 511;
    out_e[((size_t)(31 * 512 + d)) * 1024 + t] = ldin(cb, (size_t)d * 512 + id, flag);
}

// ---------------------------------------------------------------------------
extern "C" void kernel_launch(void* const* d_in, const int* in_sizes, int n_in,
                              void* d_out, int out_size, void* d_ws, size_t ws_size,
                              hipStream_t stream) {
    const void* x  = d_in[0];
    const void* We = d_in[1];
    const void* be = d_in[2];
    const void* Wd = d_in[3];
    const void* bd = d_in[4];
    const void* cb = d_in[5];

    float* out   = (float*)d_out;
    float* out_r = out;                       // 1,572,864 fp32 (6.29 MB)
    float* out_z = out + 1572864;             // 16,777,216 fp32
    float* out_e = out + 18350080;            // 16,777,216 fp32

    // Read-mostly tables in out_r (recon overwrites during k_post; nothing in
    // k_post reads them — rescore uses raw cb):
    char* Rb = (char*)out_r;
    float* cbT           = (float*)(Rb);                    // 1,048,576 B
    float* cWe           = (float*)(Rb + 1048576);          //    98,304 B
    float* cbe           = (float*)(Rb + 1146880);          //     2,048 B
    float* cWd           = (float*)(Rb + 1148928);          //    98,304 B
    float* cbd           = (float*)(Rb + 1247232);          //        64 B
    unsigned short* cbHS = (unsigned short*)(Rb + 1247296); //   524,288 B (swizzled)
    unsigned short* cbLS = (unsigned short*)(Rb + 1771584); //   524,288 B (swizzled)
    unsigned short* WeswzH=(unsigned short*)(Rb + 2295872); //    65,536 B
    unsigned short* WeswzL=(unsigned short*)(Rb + 2361408); //    65,536 B

    // Tail scratch: prefer d_ws; else last 256 KB of out_e (fixup required).
    int tailWS = (ws_size >= 262144) ? 1 : 0;
    char* Tbase = tailWS ? (char*)d_ws : ((char*)out_e + 66846720);
    int skipTail = tailWS ? 0 : 1;
    int*    idx  = (int*)   (Tbase);            // 131,072 B
    float*  U    = (float*) (Tbase + 131072);   //  98,304 B
    float*  w2   = (float*) (Tbase + 229376);   //   2,048 B
    double* w2d  = (double*)(Tbase + 231424);   //   4,096 B
    int*    flag = (int*)   (Tbase + 235520);   //      64 B
    int*    scnt = (int*)   (Tbase + 235584);   //      64 B
    int*    spos = (int*)   (Tbase + 235648);   //  16,384 B

    k_sniff<<<1, 1024, 0, stream>>>(cb, flag, scnt);
    k_prepAll<<<403, 256, 0, stream>>>(We, be, Wd, bd, cb, flag,
                                       cWe, cbe, cWd, cbd,
                                       cbT, cbHS, cbLS, WeswzH, WeswzL,
                                       w2, w2d, U);
    k_main<<<512, 512, 0, stream>>>(x, WeswzH, WeswzL, cbe, flag, cbHS, cbLS,
                                    cbT, w2, out_z, out_e, idx, scnt, spos,
                                    skipTail);
    k_post<<<384, 256, 0, stream>>>(out_z, cb, w2d, idx, scnt, spos, U, flag,
                                    out_e, out_r, skipTail);
    if (skipTail)
        k_fixup<<<64, 1024, 0, stream>>>(cb, flag, idx, out_e);
}

// Round 14
// 261.625 us; speedup vs baseline: 1.4897x; 1.4897x over previous
//
#include <hip/hip_runtime.h>
#include <hip/hip_bf16.h>

// B=32, C=3, H=W=128, D=512, K=512, S=4, NPOS=32768
#define NPOS 32768
#define EPS_GAP 4e-3f
#define MAXSUS 4096

typedef __attribute__((ext_vector_type(8))) short short8;
typedef __attribute__((ext_vector_type(4))) float floatx4;

static __device__ __forceinline__ float bfu(unsigned short h) {
    return __uint_as_float(((unsigned int)h) << 16);
}
static __device__ __forceinline__ unsigned short f2bf(float f) {
    unsigned int u = __float_as_uint(f);
    u = (u + 0x7fffu + ((u >> 16) & 1u)) >> 16;   // RNE
    return (unsigned short)u;
}
static __device__ __forceinline__ float ldin(const void* p, size_t i, int flag) {
    return flag ? bfu(((const unsigned short*)p)[i]) : ((const float*)p)[i];
}

// LDS-only barrier: drains ds ops (lgkmcnt) but leaves global loads/stores
// in flight across the barrier (no vmcnt(0) drain).
static __device__ __forceinline__ void ldsbar() {
    asm volatile("s_waitcnt lgkmcnt(0)" ::: "memory");
    __builtin_amdgcn_s_barrier();
    asm volatile("" ::: "memory");
}

// Swizzled B-fragment offset for the CODEBOOK (units: shorts).
static __device__ __forceinline__ size_t swzoff(int k, int d) {
    return (size_t)(d >> 5) * 16384 + (size_t)(k >> 4) * 512
         + (size_t)((((d >> 3) & 3) * 16 + (k & 15)) * 8) + (d & 7);
}

// ---------------------------------------------------------------------------
// FUSED prep v2: sniff is computed PER-BLOCK (no separate k_sniff launch).
// Every block derives the same flag from codebook columns 0..63 (64KB,
// L2-hot); the decision margin (norms ~512 vs garbage, window [100,2000])
// is far beyond any summation-order sensitivity. bid 0 publishes flag + scnt.
// Roles (209 blocks):
//   bid 0        : cbe copy + flag/scnt store
//   bid 1..64    : prepcb  (cb -> cbT; cbHS/cbLS swizzled bf16)
//   bid 65..72   : w2      (column norms fp32+fp64)
//   bid 73..200  : udec    (decoder LUT U[k][48], reads raw cb/Wd/bd)
//   bid 201..208 : weswz   (We -> H/L bf16 B-fragment tables, K-padded 64)
// ---------------------------------------------------------------------------
__global__ __launch_bounds__(256) void k_prepAll(
        const void* __restrict__ We, const void* __restrict__ be,
        const void* __restrict__ Wd, const void* __restrict__ bd,
        const void* __restrict__ cb,
        int* __restrict__ flagp, int* __restrict__ scnt,
        float* __restrict__ cbe,
        float* __restrict__ cbT, unsigned short* __restrict__ cbHS,
        unsigned short* __restrict__ cbLS,
        unsigned short* __restrict__ WeswzH, unsigned short* __restrict__ WeswzL,
        float* __restrict__ w2, double* __restrict__ w2d,
        float* __restrict__ U) {
    __shared__ float tile[64][65];
    __shared__ double sd[256];
    __shared__ float sf[256];
    __shared__ int sflag;
    const int bid = blockIdx.x;
    const int t = threadIdx.x;

    // ---- per-block sniff (columns 0..63 of cb interpreted as bf16) ----
    {
        const unsigned short* u = (const unsigned short*)cb;
        const int kc = t & 63, g = t >> 6;       // 4 groups x 128 d
        float a = 0.f;
        for (int d = g * 128; d < g * 128 + 128; ++d) {
            float v = bfu(u[(size_t)d * 512 + kc]);
            a = fmaf(v, v, a);
        }
        sf[t] = a;
        __syncthreads();
        if (t < 64) {
            float s = sf[t] + sf[t + 64] + sf[t + 128] + sf[t + 192];
            int ok = (s >= 100.f && s <= 2000.f) ? 1 : 0;
            unsigned long long m = __ballot(ok);
            if (t == 0) sflag = (m == ~0ull) ? 1 : 0;
        }
        __syncthreads();
    }
    const int flag = sflag;

    if (bid == 0) {
        // ---- publish flag/scnt for downstream kernels; copy bias ----
        if (t == 0) { *flagp = flag; *scnt = 0; }
        cbe[t]       = ldin(be, t, flag);
        cbe[t + 256] = ldin(be, t + 256, flag);
    } else if (bid < 65) {
        // ---- prepcb ----
        const int bb = bid - 1;
        const int D0 = (bb >> 3) * 64, K0 = (bb & 7) * 64;
        for (int it = 0; it < 16; ++it) {
            int r = (t >> 6) + 4 * it, c = t & 63;
            tile[r][c] = ldin(cb, (size_t)(D0 + r) * 512 + K0 + c, flag);
        }
        __syncthreads();
        for (int it = 0; it < 16; ++it) {
            int r = (t >> 6) + 4 * it, c = t & 63;
            float v = tile[c][r];
            int k = K0 + r, d = D0 + c;
            cbT[(size_t)k * 512 + d] = v;
            size_t o2 = swzoff(k, d);
            unsigned short h = f2bf(v);
            cbHS[o2] = h;
            cbLS[o2] = f2bf(v - bfu(h));
        }
    } else if (bid < 73) {
        // ---- w2 ----
        const int k = (bid - 65) * 64 + (t & 63);
        const int g = t >> 6;                  // 4 groups x 128 d
        double acc = 0.0;
        for (int d = g * 128; d < g * 128 + 128; ++d) {
            double v = (double)ldin(cb, (size_t)d * 512 + k, flag);
            acc += v * v;
        }
        sd[t] = acc;
        __syncthreads();
        if (t < 64) {
            double a = sd[t] + sd[t + 64] + sd[t + 128] + sd[t + 192];
            w2[k] = (float)a;
            w2d[k] = a;
        }
    } else if (bid < 201) {
        // ---- udec: U[k][c*16+u*4+v] = sum_d cb[d][k]*Wd[c][d][3-u][3-v]+bd[c]
        const int kk = (bid - 73) * 4 + (t >> 6);
        const int lane = t & 63;
        const int j = lane >> 2, dpart = lane & 3;
        const int u = (j >> 2) & 3, v = j & 3;
        int woff[3];
        #pragma unroll
        for (int m = 0; m < 3; ++m) woff[m] = m * 8192 + (3 - u) * 4 + (3 - v);
        float a0 = 0.f, a1 = 0.f, a2 = 0.f;
        for (int i = 0; i < 128; ++i) {
            int d = dpart * 128 + i;
            float cw = ldin(cb, (size_t)d * 512 + kk, flag);
            a0 = fmaf(cw, ldin(Wd, (size_t)(woff[0] + d * 16), flag), a0);
            a1 = fmaf(cw, ldin(Wd, (size_t)(woff[1] + d * 16), flag), a1);
            a2 = fmaf(cw, ldin(Wd, (size_t)(woff[2] + d * 16), flag), a2);
        }
        a0 += __shfl_xor(a0, 1); a0 += __shfl_xor(a0, 2);
        a1 += __shfl_xor(a1, 1); a1 += __shfl_xor(a1, 2);
        a2 += __shfl_xor(a2, 1); a2 += __shfl_xor(a2, 2);
        if (dpart == 0) {
            U[kk * 48 +  0 + j] = a0 + ldin(bd, 0, flag);
            U[kk * 48 + 16 + j] = a1 + ldin(bd, 1, flag);
            U[kk * 48 + 32 + j] = a2 + ldin(bd, 2, flag);
        }
    } else {
        // ---- weswz: We[d][q<48] (q 48..63 zero) -> H/L B-fragment tables.
        const int bid2 = bid - 201;            // 0..7
        for (int it = 0; it < 16; ++it) {
            int e = bid2 * 4096 + it * 256 + t;    // over 512*64
            int d = e >> 6, q = e & 63;
            float w = (q < 48) ? ldin(We, (size_t)d * 48 + q, flag) : 0.f;
            unsigned short h = f2bf(w);
            unsigned short l = f2bf(w - bfu(h));
            size_t off = (size_t)((d >> 5) * 2 + ((d >> 4) & 1)) * 1024
                       + (size_t)(q >> 5) * 512
                       + (size_t)((((q >> 3) & 3) * 16 + (d & 15)) * 8) + (q & 7);
            WeswzH[off] = h;
            WeswzL[off] = l;
        }
    }
}

// ---------------------------------------------------------------------------
// conv via MFMA (r12-verified): Z[64 pos][32 d] = patch x We, split-precision.
// ---------------------------------------------------------------------------
static __device__ __forceinline__ void conv_mfma(
        const unsigned short* __restrict__ patchH, const unsigned short* __restrict__ patchL,
        const unsigned short* __restrict__ WeH, const unsigned short* __restrict__ WeL,
        const float* __restrict__ cbe, int dc, int wave, int lane, int flag,
        unsigned short* __restrict__ zq, float* __restrict__ out_z, int b, int SP0) {
    const int mt = wave >> 1, nt = wave & 1;
    const int quad = lane >> 4, lcol = lane & 15;
    const int row = mt * 16 + lcol;
    short8 aH0 = *(const short8*)(patchH + row * 72 + quad * 8);
    short8 aH1 = *(const short8*)(patchH + row * 72 + 32 + quad * 8);
    const unsigned short* wb = WeH + (size_t)((dc >> 5) * 2 + nt) * 1024 + lane * 8;
    short8 bH0 = *(const short8*)(wb);
    short8 bH1 = *(const short8*)(wb + 512);
    floatx4 c = (floatx4){0.f, 0.f, 0.f, 0.f};
    c = __builtin_amdgcn_mfma_f32_16x16x32_bf16(aH0, bH0, c, 0, 0, 0);
    c = __builtin_amdgcn_mfma_f32_16x16x32_bf16(aH1, bH1, c, 0, 0, 0);
    if (!flag) {   // fp32 inputs: add L*H and H*L terms
        short8 aL0 = *(const short8*)(patchL + row * 72 + quad * 8);
        short8 aL1 = *(const short8*)(patchL + row * 72 + 32 + quad * 8);
        const unsigned short* wl = WeL + (size_t)((dc >> 5) * 2 + nt) * 1024 + lane * 8;
        short8 bL0 = *(const short8*)(wl);
        short8 bL1 = *(const short8*)(wl + 512);
        c = __builtin_amdgcn_mfma_f32_16x16x32_bf16(aL0, bH0, c, 0, 0, 0);
        c = __builtin_amdgcn_mfma_f32_16x16x32_bf16(aL1, bH1, c, 0, 0, 0);
        c = __builtin_amdgcn_mfma_f32_16x16x32_bf16(aH0, bL0, c, 0, 0, 0);
        c = __builtin_amdgcn_mfma_f32_16x16x32_bf16(aH1, bL1, c, 0, 0, 0);
    }
    const int d = nt * 16 + lcol;
    const float bias = cbe[dc + d];
    const int p0 = mt * 16 + quad * 4;        // 4 consecutive positions
    float zf[4];
    #pragma unroll
    for (int r = 0; r < 4; ++r) {
        float z = fmaxf(c[r] + bias, 0.f);
        unsigned short h = f2bf(z);
        unsigned short l = f2bf(z - bfu(h));
        zq[(p0 + r) * 40 + d] = h;
        zq[2560 + (p0 + r) * 40 + d] = l;
        zf[r] = bfu(h) + bfu(l);
    }
    *(float4*)(out_z + (size_t)(b * 512 + dc + d) * 1024 + SP0 + p0) =
        (float4){zf[0], zf[1], zf[2], zf[3]};
}

// Each wave handles code-tiles wave*4+j (j=0..3): acc[4 mt][4 j]. (r12 verbatim)
static __device__ __forceinline__ void mfma_step(
        const unsigned short* __restrict__ zq,
        const unsigned short* __restrict__ cbHS,
        const unsigned short* __restrict__ cbLS,
        int dcPrev, int wave, int quad, int lcol, int flag, floatx4 (&acc)[4][4]) {
    const int lane = quad * 16 + lcol;
    short8 aH[4], aL[4];
    #pragma unroll
    for (int mt = 0; mt < 4; ++mt) {
        aH[mt] = *(const short8*)(zq + (mt * 16 + lcol) * 40 + quad * 8);
        aL[mt] = *(const short8*)(zq + 2560 + (mt * 16 + lcol) * 40 + quad * 8);
    }
    const unsigned short* fbH = cbHS + (size_t)dcPrev * 512 + (size_t)(wave * 4) * 512 + lane * 8;
    #pragma unroll
    for (int j = 0; j < 4; ++j) {
        short8 bH = *(const short8*)(fbH + j * 512);
        #pragma unroll
        for (int mt = 0; mt < 4; ++mt) {
            acc[mt][j] = __builtin_amdgcn_mfma_f32_16x16x32_bf16(aH[mt], bH, acc[mt][j], 0, 0, 0);
            acc[mt][j] = __builtin_amdgcn_mfma_f32_16x16x32_bf16(aL[mt], bH, acc[mt][j], 0, 0, 0);
        }
    }
    if (!flag) {   // fp32 inputs: third term zh*cbL
        const unsigned short* fbL = cbLS + (size_t)dcPrev * 512 + (size_t)(wave * 4) * 512 + lane * 8;
        #pragma unroll
        for (int j = 0; j < 4; ++j) {
            short8 bL = *(const short8*)(fbL + j * 512);
            #pragma unroll
            for (int mt = 0; mt < 4; ++mt)
                acc[mt][j] = __builtin_amdgcn_mfma_f32_16x16x32_bf16(aH[mt], bL, acc[mt][j], 0, 0, 0);
        }
    }
}

// best/second combine: (a1,ak,a2) <- merge (o1,ok,o2). Order-independent
// tournament (ties -> gap 0), so reshaping the reduction tree is safe.
static __device__ __forceinline__ void bmerge(float& a1, int& ak, float& a2,
                                              float o1, int ok, float o2) {
    if (o1 < a1)      { a2 = fminf(a1, o2); a1 = o1; ak = ok; }
    else if (o1 > a1) { a2 = fminf(a2, o1); }
    else              { a2 = a1; if (ok < ak) ak = ok; }
}

// ---------------------------------------------------------------------------
// k_main v16 = r12 VERBATIM (MFMA conv, inline B loads, no prefetch — the
// proven 90us configuration; r13's register prefetch spilled to scratch:
// FETCH 7.9->138MB, WRITE 131->590MB, 2.6x regression).
// LDS: patchH 9216 | patchL 9216 | zb 2 pairs x 10240 = 38912B.
// ---------------------------------------------------------------------------
__global__ __launch_bounds__(512, 4) void k_main(
        const void* __restrict__ x, const unsigned short* __restrict__ WeswzH,
        const unsigned short* __restrict__ WeswzL,
        const float* __restrict__ cbe, const int* __restrict__ flagp,
        const unsigned short* __restrict__ cbHS, const unsigned short* __restrict__ cbLS,
        const float* __restrict__ cbT, const float* __restrict__ w2,
        float* __restrict__ out_z, float* __restrict__ out_e,
        int* __restrict__ idx, int* __restrict__ scnt, int* __restrict__ spos,
        int skipTail) {
    __shared__ __align__(16) char smc[38912];
    unsigned short* patchH = (unsigned short*)smc;            // [64][72]
    unsigned short* patchL = (unsigned short*)(smc + 9216);   // [64][72]
    unsigned short* zb = (unsigned short*)(smc + 18432);      // 2 pairs x 5120 shorts

    const int t = threadIdx.x;
    const int bid = blockIdx.x;
    const int q = ((bid & 7) << 6) | (bid >> 3);   // XCD co-location swizzle
    const int P0 = q * 64;
    const int b = P0 >> 10, SP0 = P0 & 1023;
    const int flag = *flagp;
    const int wave = t >> 6, lane = t & 63;
    const int quad = lane >> 4, lcol = lane & 15;

    // stage x patches once as bf16 H/L, K-padded with zeros (q 48..63)
    for (int e = t; e < 4096; e += 512) {
        int pid = e >> 6, qq = e & 63;
        float xv = 0.f;
        if (qq < 48) {
            int c = qq >> 4, r = (qq >> 2) & 3, s = qq & 3;
            int pos = P0 + pid;
            int bb = pos >> 10, sp = pos & 1023, i = sp >> 5, j = sp & 31;
            xv = ldin(x, ((bb * 3 + c) * 128 + (i * 4 + r)) * 128 + (j * 4 + s), flag);
        }
        unsigned short h = f2bf(xv);
        patchH[pid * 72 + qq] = h;
        patchL[pid * 72 + qq] = f2bf(xv - bfu(h));
    }

    floatx4 acc[4][4];
    #pragma unroll
    for (int mt = 0; mt < 4; ++mt)
        #pragma unroll
        for (int j = 0; j < 4; ++j) acc[mt][j] = (floatx4){0.f, 0.f, 0.f, 0.f};

    ldsbar();
    conv_mfma(patchH, patchL, WeswzH, WeswzL, cbe, 0, wave, lane, flag,
              zb, out_z, b, SP0);                             // chunk 0 -> pair 0
    for (int dc = 32; dc < 512; dc += 32) {
        ldsbar();
        const int p = (dc >> 5) & 1;
        conv_mfma(patchH, patchL, WeswzH, WeswzL, cbe, dc, wave, lane, flag,
                  zb + p * 5120, out_z, b, SP0);
        mfma_step(zb + (p ^ 1) * 5120, cbHS, cbLS, dc - 32, wave, quad, lcol, flag, acc);
    }
    ldsbar();
    mfma_step(zb + 5120, cbHS, cbLS, 480, wave, quad, lcol, flag, acc);

    // ---- epilogue: per-lane best/second over its 4 codes, then shuffle ----
    float s1[4][4], s2[4][4]; int k1[4][4];
    #pragma unroll
    for (int mt = 0; mt < 4; ++mt)
        #pragma unroll
        for (int r = 0; r < 4; ++r) { s1[mt][r] = 1e30f; s2[mt][r] = 1e30f; k1[mt][r] = 511; }
    #pragma unroll
    for (int j = 0; j < 4; ++j) {
        int code = (wave * 4 + j) * 16 + lcol;
        float wk = w2[code];
        #pragma unroll
        for (int mt = 0; mt < 4; ++mt)
            #pragma unroll
            for (int r = 0; r < 4; ++r) {
                float s = wk - 2.f * acc[mt][j][r];
                bmerge(s1[mt][r], k1[mt][r], s2[mt][r], s, code, 1e30f);
            }
    }
    // overlay reduction arrays on patchH region (patch dead after last conv+bar)
    float* sS1 = (float*)smc;             // [64 pos][8 wave]
    int*   sK1 = (int*)(smc + 2048);
    float* sS2 = (float*)(smc + 4096);
    int*   ii  = (int*)(smc + 6144);      // [64]
    #pragma unroll
    for (int mt = 0; mt < 4; ++mt)
        #pragma unroll
        for (int r = 0; r < 4; ++r) {
            float a1 = s1[mt][r], a2 = s2[mt][r]; int ak = k1[mt][r];
            #pragma unroll
            for (int m = 1; m < 16; m <<= 1) {
                float o1 = __shfl_xor(a1, m);
                float o2 = __shfl_xor(a2, m);
                int   ok = __shfl_xor(ak, m);
                bmerge(a1, ak, a2, o1, ok, o2);
            }
            if (lcol == 0) {
                int pos = mt * 16 + quad * 4 + r;
                sS1[pos * 8 + wave] = a1;
                sK1[pos * 8 + wave] = ak;
                sS2[pos * 8 + wave] = a2;
            }
        }
    __syncthreads();
    if (t < 64) {
        float a1 = sS1[t * 8]; int ak = sK1[t * 8]; float a2 = sS2[t * 8];
        #pragma unroll
        for (int w = 1; w < 8; ++w)
            bmerge(a1, ak, a2, sS1[t * 8 + w], sK1[t * 8 + w], sS2[t * 8 + w]);
        ak &= 511;
        ii[t] = ak;
        unsigned int flagged = 0u;
        if (a2 - a1 < EPS_GAP) {
            int slot = atomicAdd(scnt, 1);
            if (slot < MAXSUS) { spos[slot] = P0 + t; flagged = 1u; }
        }
        idx[P0 + t] = (int)((unsigned)ak | (flagged << 31));
    }
    __syncthreads();

    // ---- fused emb: out_e[b][d][SP0+sp] = cbT[ii[sp]][d] ----
    const int sp = t & 63, dq = t >> 6;   // 8 groups x 64 d
    const float* row = cbT + (size_t)ii[sp] * 512;
    const size_t obase = ((size_t)b * 512) * 1024 + SP0 + sp;
    for (int d0 = dq * 64; d0 < dq * 64 + 64; d0 += 4) {
        if (skipTail && b == 31 && d0 >= 448) break;
        float4 v = *(const float4*)(row + d0);
        out_e[obase + (size_t)(d0    ) * 1024] = v.x;
        out_e[obase + (size_t)(d0 + 1) * 1024] = v.y;
        out_e[obase + (size_t)(d0 + 2) * 1024] = v.z;
        out_e[obase + (size_t)(d0 + 3) * 1024] = v.w;
    }
}

// ---------------------------------------------------------------------------
// FUSED post: recon (bid 0..127) ∥ rescore (bid 128..383) in one launch.
// ---------------------------------------------------------------------------
__global__ __launch_bounds__(256) void k_post(
        const float* __restrict__ out_z, const void* __restrict__ cb,
        const double* __restrict__ w2d, int* __restrict__ idx,
        const int* __restrict__ scnt, const int* __restrict__ spos,
        const float* __restrict__ U, const int* __restrict__ flagp,
        float* __restrict__ out_e, float* __restrict__ out_r, int skipTail) {
    __shared__ float zsh[512];
    __shared__ float rs[256];
    __shared__ int rk[256];
    __shared__ int bc[2];
    const int bid = blockIdx.x;
    const int t = threadIdx.x;

    if (bid < 128) {
        // ---- recon role ----
        const int pos = bid * 256 + t;
        const int v0 = idx[pos];
        if (v0 >= 0) {
            const int id = v0 & 511;
            const int b = pos >> 10, sp = pos & 1023, i = sp >> 5, j = sp & 31;
            const float* u = &U[(size_t)id * 48];
            #pragma unroll
            for (int c = 0; c < 3; ++c)
                #pragma unroll
                for (int uu = 0; uu < 4; ++uu) {
                    float4 q = *(const float4*)(&u[c * 16 + uu * 4]);
                    float4 o;
                    o.x = 1.f / (1.f + __expf(-q.x));
                    o.y = 1.f / (1.f + __expf(-q.y));
                    o.z = 1.f / (1.f + __expf(-q.z));
                    o.w = 1.f / (1.f + __expf(-q.w));
                    *(float4*)(&out_r[((size_t)((b * 3 + c) * 128) + (i * 4 + uu)) * 128 + j * 4]) = o;
                }
        }
        return;
    }

    // ---- rescore role (256 blocks) ----
    const int flag = *flagp;
    int n = *scnt; if (n > MAXSUS) n = MAXSUS;
    for (int s = bid - 128; s < n; s += 256) {
        int p = spos[s] & 32767;
        int b = p >> 10, sp = p & 1023;
        __syncthreads();
        zsh[t]       = out_z[(size_t)(b * 512 + t) * 1024 + sp];
        zsh[t + 256] = out_z[(size_t)(b * 512 + t + 256) * 1024 + sp];
        __syncthreads();
        float bs = 1e30f; int bk = 511;
        for (int cc = 0; cc < 2; ++cc) {
            int k = t + cc * 256;
            double a = 0.0;
            for (int d = 0; d < 512; ++d)
                a = fma((double)zsh[d], (double)ldin(cb, (size_t)d * 512 + k, flag), a);
            float sc = (float)(w2d[k] - 2.0 * a);
            if (sc < bs || (sc == bs && k < bk)) { bs = sc; bk = k; }
        }
        rs[t] = bs; rk[t] = bk;
        __syncthreads();
        for (int str = 128; str > 0; str >>= 1) {
            if (t < str) {
                float so = rs[t + str]; int ko = rk[t + str];
                if (so < rs[t] || (so == rs[t] && ko < rk[t])) { rs[t] = so; rk[t] = ko; }
            }
            __syncthreads();
        }
        if (t == 0) {
            int kstar = rk[0] & 511;
            int old = idx[p] & 511;
            bc[0] = kstar; bc[1] = (kstar != old);
            idx[p] = kstar;                       // clears suspect flag too
        }
        __syncthreads();
        const int kk = bc[0];
        if (bc[1]) {
            for (int d = t; d < 512; d += 256) {
                if (skipTail && b == 31 && d >= 448) continue;
                out_e[(size_t)(b * 512 + d) * 1024 + sp] = ldin(cb, (size_t)d * 512 + kk, flag);
            }
        }
        // recon for this suspect (recon role skipped it) — always write
        if (t < 48) {
            float q = U[(size_t)kk * 48 + t];
            float o = 1.f / (1.f + __expf(-q));
            int c = t >> 4, uu = (t >> 2) & 3, vv = t & 3;
            int i = sp >> 5, j = sp & 31;
            out_r[((size_t)((b * 3 + c) * 128) + (i * 4 + uu)) * 128 + j * 4 + vv] = o;
        }
    }
}

// ---------------------------------------------------------------------------
// Widened fixup: 64 blocks, one d-row each. Coalesced idx read + row write.
// ---------------------------------------------------------------------------
__global__ __launch_bounds__(1024) void k_fixup(
        const void* __restrict__ cb, const int* __restrict__ flagp,
        const int* __restrict__ idx, float* __restrict__ out_e) {
    const int t = threadIdx.x;
    const int d = 448 + blockIdx.x;
    const int flag = *flagp;
    const int id = idx[31744 + t] & 511;
    out_e[((size_t)(31 * 512 + d)) * 1024 + t] = ldin(cb, (size_t)d * 512 + id, flag);
}

// ---------------------------------------------------------------------------
extern "C" void kernel_launch(void* const* d_in, const int* in_sizes, int n_in,
                              void* d_out, int out_size, void* d_ws, size_t ws_size,
                              hipStream_t stream) {
    const void* x  = d_in[0];
    const void* We = d_in[1];
    const void* be = d_in[2];
    const void* Wd = d_in[3];
    const void* bd = d_in[4];
    const void* cb = d_in[5];

    float* out   = (float*)d_out;
    float* out_r = out;                       // 1,572,864 fp32 (6.29 MB)
    float* out_z = out + 1572864;             // 16,777,216 fp32
    float* out_e = out + 18350080;            // 16,777,216 fp32

    // Read-mostly tables in out_r (recon overwrites during k_post; nothing in
    // k_post reads them — rescore uses raw cb). Offsets unchanged from r12.
    char* Rb = (char*)out_r;
    float* cbT           = (float*)(Rb);                    // 1,048,576 B
    float* cbe           = (float*)(Rb + 1146880);          //     2,048 B
    unsigned short* cbHS = (unsigned short*)(Rb + 1247296); //   524,288 B (swizzled)
    unsigned short* cbLS = (unsigned short*)(Rb + 1771584); //   524,288 B (swizzled)
    unsigned short* WeswzH=(unsigned short*)(Rb + 2295872); //    65,536 B
    unsigned short* WeswzL=(unsigned short*)(Rb + 2361408); //    65,536 B

    // Tail scratch: prefer d_ws; else last 256 KB of out_e (fixup required).
    int tailWS = (ws_size >= 262144) ? 1 : 0;
    char* Tbase = tailWS ? (char*)d_ws : ((char*)out_e + 66846720);
    int skipTail = tailWS ? 0 : 1;
    int*    idx  = (int*)   (Tbase);            // 131,072 B
    float*  U    = (float*) (Tbase + 131072);   //  98,304 B
    float*  w2   = (float*) (Tbase + 229376);   //   2,048 B
    double* w2d  = (double*)(Tbase + 231424);   //   4,096 B
    int*    flag = (int*)   (Tbase + 235520);   //      64 B
    int*    scnt = (int*)   (Tbase + 235584);   //      64 B
    int*    spos = (int*)   (Tbase + 235648);   //  16,384 B

    k_prepAll<<<209, 256, 0, stream>>>(We, be, Wd, bd, cb, flag, scnt,
                                       cbe, cbT, cbHS, cbLS, WeswzH, WeswzL,
                                       w2, w2d, U);
    k_main<<<512, 512, 0, stream>>>(x, WeswzH, WeswzL, cbe, flag, cbHS, cbLS,
                                    cbT, w2, out_z, out_e, idx, scnt, spos,
                                    skipTail);
    k_post<<<384, 256, 0, stream>>>(out_z, cb, w2d, idx, scnt, spos, U, flag,
                                    out_e, out_r, skipTail);
    if (skipTail)
        k_fixup<<<64, 1024, 0, stream>>>(cb, flag, idx, out_e);
}